// Round 17
// baseline (1158.214 us; speedup 1.0000x reference)
//
#include <hip/hip_runtime.h>
#include <hip/hip_fp16.h>

#define N_NODES 500000
#define N_EDGES 1000000
#define N_GRAPHS 20000

typedef _Float16 f16x8 __attribute__((ext_vector_type(8)));
typedef float f32x4 __attribute__((ext_vector_type(4)));

__global__ __launch_bounds__(256) void fill_u32(unsigned* p, unsigned v, int n) {
  int i = blockIdx.x * 256 + threadIdx.x;
  if (i < n) p[i] = v;
}

__global__ __launch_bounds__(256) void hist_dst(const int* __restrict__ dst, int* cnt, int e) {
  int i = blockIdx.x * 256 + threadIdx.x;
  if (i < e) atomicAdd(&cnt[dst[i]], 1);
}

// ---- 2-level exclusive scan over deg[N] (1024 elems/block) ----
__global__ __launch_bounds__(256) void scanA(const int* __restrict__ deg, int* __restrict__ loc,
                                             int* __restrict__ partials, int n) {
  __shared__ int ts[256];
  int b = blockIdx.x, t = threadIdx.x;
  int base = b * 1024 + t * 4;
  int v[4], s = 0;
#pragma unroll
  for (int j = 0; j < 4; ++j) {
    v[j] = (base + j < n) ? deg[base + j] : 0;
    s += v[j];
  }
  ts[t] = s;
  __syncthreads();
  for (int off = 1; off < 256; off <<= 1) {
    int x = (t >= off) ? ts[t - off] : 0;
    __syncthreads();
    ts[t] += x;
    __syncthreads();
  }
  if (t == 255) partials[b] = ts[255];
  int run = ts[t] - s;  // exclusive
#pragma unroll
  for (int j = 0; j < 4; ++j) {
    if (base + j < n) loc[base + j] = run;
    run += v[j];
  }
}

__global__ __launch_bounds__(512) void scanB(int* partials, int nb) {
  __shared__ int s[512];
  int t = threadIdx.x;
  s[t] = (t < nb) ? partials[t] : 0;
  __syncthreads();
  if (t == 0) {
    int run = 0;
    for (int i = 0; i < nb; ++i) { int v = s[i]; s[i] = run; run += v; }
  }
  __syncthreads();
  if (t < nb) partials[t] = s[t];
}

__global__ __launch_bounds__(256) void scanC(int* __restrict__ rowptr, const int* __restrict__ partials,
                                             int* __restrict__ cur, int n, int e) {
  int i = blockIdx.x * 256 + threadIdx.x;
  if (i < n) {
    int v = rowptr[i] + partials[i >> 10];
    rowptr[i] = v;
    cur[i] = v;
  }
  if (i == 0) rowptr[n] = e;
}

__global__ __launch_bounds__(256) void dinv_k(const int* __restrict__ rowptr, float* dinv, int n) {
  int i = blockIdx.x * 256 + threadIdx.x;
  if (i < n) dinv[i] = rsqrtf(1.0f + (float)(rowptr[i + 1] - rowptr[i]));
}

__global__ __launch_bounds__(256) void bucket(const int* __restrict__ src, const int* __restrict__ dst,
                                              int* __restrict__ cur, int* __restrict__ ssrc, int e) {
  int i = blockIdx.x * 256 + threadIdx.x;
  if (i < e) ssrc[atomicAdd(&cur[dst[i]], 1)] = src[i];
}

// ell[n] = {deg, s0, s1, s2}
__global__ __launch_bounds__(256) void ell_build(const int* __restrict__ rowptr,
                                                 const int* __restrict__ ssrc,
                                                 int4* __restrict__ ell, int n) {
  int i = blockIdx.x * 256 + threadIdx.x;
  if (i >= n) return;
  int r0 = rowptr[i], r1 = rowptr[i + 1];
  int deg = r1 - r0;
  int4 e;
  e.x = deg;
  e.y = (deg > 0) ? ssrc[r0] : 0;
  e.z = (deg > 1) ? ssrc[r0 + 1] : 0;
  e.w = (deg > 2) ? ssrc[r0 + 2] : 0;
  ell[i] = e;
}

// gstart[g] = first node index of graph g (batch sorted); gstart[G] = N
__global__ __launch_bounds__(256) void graph_starts(const int* __restrict__ batch,
                                                    int* __restrict__ gstart, int n) {
  int i = blockIdx.x * 256 + threadIdx.x;
  if (i < n) {
    int b = batch[i];
    int bp = (i == 0) ? -1 : batch[i - 1];
    for (int g = bp + 1; g <= b; ++g) gstart[g] = i;
  } else if (i == n) {
    int bl = batch[n - 1];
    for (int g = bl + 1; g <= N_GRAPHS; ++g) gstart[g] = n;
  }
}

// WT[c][k'] = f16(W[k][c]), rows stride STRIDE (zero beyond KPL / Nout).
// CW>0: chunk layout, k = 78*(k'/CW) + k'%CW, valid (k'%CW)<78.
template <int CW>
__global__ __launch_bounds__(256) void wt_conv(const float* __restrict__ W, _Float16* __restrict__ WT,
                                               int K, int Nout, int ldw, int KPL, int STRIDE, int total) {
  int i = blockIdx.x * 256 + threadIdx.x;
  if (i >= total) return;
  int c = i / STRIDE, kp = i - c * STRIDE;
  int k = kp; bool valid = kp < KPL;
  if (CW) { int blk = kp / CW, r = kp - blk * CW; k = blk * 78 + r; valid = valid && (r < 78) && (k < K); }
  else { valid = valid && (kp < K); }
  WT[i] = (valid && c < Nout) ? (_Float16)W[(size_t)k * ldw + c] : (_Float16)0.f;
}

// Xh[n, 0:104] = f16(x[n, 0:78] * dinv[n]), zero pad to 104
__global__ __launch_bounds__(256) void xconv(const float* __restrict__ xin,
                                             const float* __restrict__ dinv,
                                             _Float16* __restrict__ Xh) {
  unsigned idx = blockIdx.x * 256u + threadIdx.x;
  if (idx >= (unsigned)N_NODES * 52u) return;
  unsigned n = idx / 52u, c2 = idx - n * 52u;
  __half2 h = __floats2half2_rn(0.f, 0.f);
  if (c2 < 39u) {
    float di = dinv[n];
    float2 v = *reinterpret_cast<const float2*>(xin + (size_t)n * 78 + 2 * c2);
    h = __floats2half2_rn(v.x * di, v.y * di);
  }
  *reinterpret_cast<__half2*>((__half*)Xh + (size_t)n * 104 + 2 * c2) = h;
}

__device__ __forceinline__ void async16(const void* g, void* l) {
  __builtin_amdgcn_global_load_lds(
      (const __attribute__((address_space(1))) void*)g,
      (__attribute__((address_space(3))) void*)l, 16, 0, 0);
}

// Async-LDS MFMA GEMM. BM=64 rows, 4 waves x 16 rows, plane = 78 output cols.
// A/B staged via global_load_lds (zero VGPR, all loads in flight), one barrier,
// pure ds_read_b128 + MFMA. blockIdx.x = plane: wt += x*78*STRIDE, bias += x*78.
// POOL=0: relu(v+b)[*rs] -> f16 out (out += x*80), coalesced via LDS tile.
// POOL=1: fused graph-pool: segmented per-column scan of the relu'd LDS tile
//         (batch sorted -> ~3 graphs/block), ~270 fp32 atomicAdds into
//         gsum[G,320] at col base x*80. No global activation write.
// OUT_MODE 1: relu(v+b) ; 3: relu(v+b)*rs[row]
template <int KPL, int STRIDE, int OUT_MODE, int POOL>
__global__ __launch_bounds__(256) void gemm_lds(
    const _Float16* __restrict__ in, const _Float16* __restrict__ WT,
    _Float16* __restrict__ outp, const float* __restrict__ rs,
    const float* __restrict__ bo, int M, int LDO,
    const int* __restrict__ batch, float* __restrict__ gsum) {
  constexpr int NS = KPL / 32;
  constexpr int SB = STRIDE * 2;                 // row bytes
  constexpr int CA = (64 * SB) / 1024;           // A chunks
  constexpr int CB = (80 * SB + 1023) / 1024;    // B chunks (last reads slack)
  __shared__ __align__(16) _Float16 As[64 * STRIDE];
  __shared__ __align__(16) _Float16 Bs[CB * 512];
  __shared__ int sBatch[POOL ? 64 : 1];
  const int tid = threadIdx.x;
  const int lane = tid & 63;
  const int wid = tid >> 6;
  const int row0 = blockIdx.y * 64;
  const _Float16* wt = WT + (size_t)(blockIdx.x * 78) * STRIDE;
  const float* bop = bo + blockIdx.x * 78;

  // ---- async stage A (64 rows) and B (80 weight rows), linear copies ----
  const char* ab = (const char*)in + (size_t)row0 * SB;
  for (int c = wid; c < CA; c += 4)
    async16(ab + (size_t)c * 1024 + lane * 16, (char*)As + c * 1024);
  const char* bb = (const char*)wt;
  for (int c = wid; c < CB; c += 4)
    async16(bb + (size_t)c * 1024 + lane * 16, (char*)Bs + c * 1024);
  __syncthreads();  // drains vmcnt before barrier

  const int r16 = lane & 15, q = lane >> 4;
  const f32x4 z4 = {0.f, 0.f, 0.f, 0.f};
  f32x4 acc[5];
#pragma unroll
  for (int nf = 0; nf < 5; ++nf) acc[nf] = z4;

#pragma unroll
  for (int s = 0; s < NS; ++s) {
    f16x8 af = *reinterpret_cast<const f16x8*>(&As[(wid * 16 + r16) * STRIDE + s * 32 + q * 8]);
#pragma unroll
    for (int nf = 0; nf < 5; ++nf) {
      f16x8 bf = *reinterpret_cast<const f16x8*>(&Bs[(nf * 16 + r16) * STRIDE + s * 32 + q * 8]);
      acc[nf] = __builtin_amdgcn_mfma_f32_16x16x32_f16(af, bf, acc[nf], 0, 0, 0);
    }
  }

  // ---- epilogue: acc -> LDS [64][80] relu tile (zero pads) ----
  __syncthreads();
  _Float16* Os = As;
#pragma unroll
  for (int j = 0; j < 4; ++j) {
    int rl = wid * 16 + q * 4 + j;
    int gr = row0 + rl;
    float sc = (OUT_MODE == 3 && gr < M) ? rs[gr] : 1.f;
#pragma unroll
    for (int nf = 0; nf < 5; ++nf) {
      int cl = nf * 16 + r16;
      float v = 0.f;
      if (cl < 78) {
        v = fmaxf(acc[nf][j] + bop[cl], 0.f);
        if (OUT_MODE == 3) v *= sc;
      }
      Os[rl * 80 + cl] = (_Float16)v;
    }
  }
  if (POOL && tid < 64) {
    int gr = row0 + tid;
    sBatch[tid] = (gr < M) ? batch[gr] : -1;
  }
  __syncthreads();

  if constexpr (POOL) {
    // segmented per-column scan (batch sorted); flush per graph-change
    if (tid < 78) {
      const int gcol = blockIdx.x * 80 + tid;
      float sum = 0.f;
      int gcur = -2;
      for (int r = 0; r < 64; ++r) {
        int g = sBatch[r];
        if (g < 0) break;
        if (g != gcur) {
          if (gcur >= 0) atomicAdd(&gsum[(size_t)gcur * 320 + gcol], sum);
          gcur = g;
          sum = 0.f;
        }
        sum += (float)Os[r * 80 + tid];
      }
      if (gcur >= 0) atomicAdd(&gsum[(size_t)gcur * 320 + gcol], sum);
    }
  } else {
    _Float16* out = outp + (size_t)blockIdx.x * 80;
    for (int i = tid; i < 640; i += 256) {
      int rl = i / 10, u = i - rl * 10;
      int gr = row0 + rl;
      if (gr < M)
        *reinterpret_cast<uint4*>(&out[(size_t)gr * LDO + u * 8]) =
            *reinterpret_cast<const uint4*>(&Os[rl * 80 + u * 8]);
    }
  }
}

// Direct-register MFMA GEMM (FC layers). Tile 128x80, 4 waves.
// BLDS=1: B staged fragment-linear in LDS. TSTORE: coalesced f16 store via LDS.
// OUT_MODE 1: relu(v+b) -> f16 ; 2: v+b -> f32
template <int KP, int OUT_MODE, int BLDS>
__global__ __launch_bounds__(256) void gemm_direct(
    const _Float16* __restrict__ in, const _Float16* __restrict__ WT,
    void* __restrict__ outp, const float* __restrict__ bo,
    int M, int Nout, int LDO) {
  constexpr int NS = KP / 32;
  constexpr bool TSTORE = (BLDS != 0) && (OUT_MODE != 2);
  constexpr int BS_BYTES = BLDS ? 5 * NS * 64 * 16 : 16;
  constexpr int SM_BYTES = TSTORE ? (BS_BYTES > 20480 ? BS_BYTES : 20480) : BS_BYTES;
  __shared__ __align__(16) char smem[SM_BYTES];
  _Float16* Bs = (_Float16*)smem;
  const int tid = threadIdx.x;
  const int lane = tid & 63;
  const int wid = tid >> 6;
  const int row0 = blockIdx.y * 128;
  const int col0 = blockIdx.x * 80;
  const _Float16* wt = WT + (size_t)col0 * KP;
  _Float16* out16 = (_Float16*)outp;
  float* out32 = (float*)outp;
  const int koff = (lane >> 4) * 8;
  const int gr0 = row0 + wid * 32 + (lane & 15);
  const bool v0 = gr0 < M, v1 = (gr0 + 16) < M;
  const _Float16* a0 = in + (size_t)gr0 * KP + koff;
  const _Float16* a1 = a0 + (size_t)16 * KP;
  const _Float16* bp = wt + (size_t)(lane & 15) * KP + koff;

  if (BLDS) {
    for (int i = tid; i < 5 * NS * 64; i += 256) {
      int l = i & 63;
      int nf = (i >> 6) % 5;
      int s = i / 320;
      int r = nf * 16 + (l & 15);
      int k = s * 32 + ((l >> 4) << 3);
      *reinterpret_cast<uint4*>(&Bs[(size_t)i * 8]) =
          *reinterpret_cast<const uint4*>(wt + (size_t)r * KP + k);
    }
    __syncthreads();
  }

  const f16x8 zf = {0, 0, 0, 0, 0, 0, 0, 0};
  const f32x4 z4 = {0.f, 0.f, 0.f, 0.f};
  f32x4 acc[2][5];
#pragma unroll
  for (int a = 0; a < 2; ++a)
#pragma unroll
    for (int b = 0; b < 5; ++b) acc[a][b] = z4;

#pragma unroll
  for (int s = 0; s < NS; ++s) {
    f16x8 af0 = v0 ? *reinterpret_cast<const f16x8*>(a0 + s * 32) : zf;
    f16x8 af1 = v1 ? *reinterpret_cast<const f16x8*>(a1 + s * 32) : zf;
    f16x8 bf[5];
#pragma unroll
    for (int nf = 0; nf < 5; ++nf) {
      if (BLDS)
        bf[nf] = *reinterpret_cast<const f16x8*>(&Bs[((size_t)(s * 5 + nf) * 64 + lane) * 8]);
      else
        bf[nf] = *reinterpret_cast<const f16x8*>(bp + (size_t)nf * 16 * KP + s * 32);
    }
#pragma unroll
    for (int nf = 0; nf < 5; ++nf) {
      acc[0][nf] = __builtin_amdgcn_mfma_f32_16x16x32_f16(af0, bf[nf], acc[0][nf], 0, 0, 0);
      acc[1][nf] = __builtin_amdgcn_mfma_f32_16x16x32_f16(af1, bf[nf], acc[1][nf], 0, 0, 0);
    }
  }

  if constexpr (TSTORE) {
    __syncthreads();
    _Float16* Os = (_Float16*)smem;
#pragma unroll
    for (int rf = 0; rf < 2; ++rf) {
#pragma unroll
      for (int j = 0; j < 4; ++j) {
        int rl = wid * 32 + rf * 16 + (lane >> 4) * 4 + j;
#pragma unroll
        for (int nf = 0; nf < 5; ++nf) {
          int cl = nf * 16 + (lane & 15);
          int oc = col0 + cl;
          float r = 0.f;
          if (oc < Nout) r = fmaxf(acc[rf][nf][j] + bo[oc], 0.f);
          Os[rl * 80 + cl] = (_Float16)r;
        }
      }
    }
    __syncthreads();
    for (int i = tid; i < 1280; i += 256) {
      int rl = i / 10, u = i - rl * 10;
      int gr = row0 + rl;
      if (gr < M)
        *reinterpret_cast<uint4*>(&out16[(size_t)gr * LDO + col0 + u * 8]) =
            *reinterpret_cast<const uint4*>(&Os[rl * 80 + u * 8]);
    }
  } else {
#pragma unroll
    for (int rf = 0; rf < 2; ++rf) {
#pragma unroll
      for (int j = 0; j < 4; ++j) {
        int gr = row0 + wid * 32 + rf * 16 + (lane >> 4) * 4 + j;
        if (gr >= M) continue;
#pragma unroll
        for (int nf = 0; nf < 5; ++nf) {
          int oc = col0 + nf * 16 + (lane & 15);
          if (oc >= Nout) continue;
          float v = acc[rf][nf][j];
          if (OUT_MODE == 1) out16[(size_t)gr * LDO + oc] = (_Float16)fmaxf(v + bo[oc], 0.f);
          else out32[(size_t)gr * LDO + oc] = v + bo[oc];
        }
      }
    }
  }
}

__device__ inline void acc8(float* a, uint4 v) {
  const __half2* h = reinterpret_cast<const __half2*>(&v);
#pragma unroll
  for (int j = 0; j < 4; ++j) {
    float2 f = __half22float2(h[j]);
    a[2 * j] += f.x;
    a[2 * j + 1] += f.y;
  }
}

// segment-sum gather; rows stride LDI f16 from hbase
template <int LDI>
__device__ inline void gather_sumT(float* a, const _Float16* hbase, unsigned n,
                                   const int4* __restrict__ ell,
                                   const int* __restrict__ rowptr,
                                   const int* __restrict__ ssrc) {
  int4 e = ell[n];
  const int deg = e.x;
  uint4 sv = *reinterpret_cast<const uint4*>(hbase + (size_t)n * LDI);
  uint4 g0, g1, g2;
  if (deg > 0) g0 = *reinterpret_cast<const uint4*>(hbase + (size_t)e.y * LDI);
  if (deg > 1) g1 = *reinterpret_cast<const uint4*>(hbase + (size_t)e.z * LDI);
  if (deg > 2) g2 = *reinterpret_cast<const uint4*>(hbase + (size_t)e.w * LDI);
  {
    const __half2* h = reinterpret_cast<const __half2*>(&sv);
#pragma unroll
    for (int j = 0; j < 4; ++j) {
      float2 f = __half22float2(h[j]);
      a[2 * j] = f.x;
      a[2 * j + 1] = f.y;
    }
  }
  if (deg > 0) acc8(a, g0);
  if (deg > 1) acc8(a, g1);
  if (deg > 2) acc8(a, g2);
  if (deg > 3) {
    int r = rowptr[n] + 3, r1 = r + deg - 3;
    for (; r + 2 <= r1; r += 2) {
      uint4 va = *reinterpret_cast<const uint4*>(hbase + (size_t)ssrc[r] * LDI);
      uint4 vb = *reinterpret_cast<const uint4*>(hbase + (size_t)ssrc[r + 1] * LDI);
      acc8(a, va);
      acc8(a, vb);
    }
    if (r < r1) {
      uint4 va = *reinterpret_cast<const uint4*>(hbase + (size_t)ssrc[r] * LDI);
      acc8(a, va);
    }
  }
}

// Input-side aggregation: Z[n] = f16(dinv[n] * (in[n] + Σ_seg in[ssrc]))
template <int LDI, int NSUB>
__global__ __launch_bounds__(256) void aggregateZ(
    const _Float16* __restrict__ in, const int4* __restrict__ ell,
    const int* __restrict__ rowptr, const int* __restrict__ ssrc,
    const float* __restrict__ dinv, _Float16* __restrict__ outZ, int ldo) {
  unsigned idx = blockIdx.x * 256u + threadIdx.x;
  if (idx >= (unsigned)N_NODES * NSUB) return;
  unsigned n = idx / NSUB, sub = idx - n * NSUB;
  float a[8];
  gather_sumT<LDI>(a, in + sub * 8u, n, ell, rowptr, ssrc);
  float di = dinv[n];
  _Float16 ov[8];
#pragma unroll
  for (int j = 0; j < 8; ++j) ov[j] = (_Float16)(di * a[j]);
  *reinterpret_cast<uint4*>(outZ + (size_t)n * ldo + sub * 8u) =
      *reinterpret_cast<const uint4*>(ov);
}

// GA[g*320+c] = f16(gsum[g*320+c] / cnt(g))
__global__ __launch_bounds__(256) void ga_scale(
    const float* __restrict__ gsum, const int* __restrict__ gstart,
    _Float16* __restrict__ GA) {
  int i = blockIdx.x * 256 + threadIdx.x;
  if (i >= N_GRAPHS * 320) return;
  int g = i / 320;
  float gi = 1.0f / fmaxf((float)(gstart[g + 1] - gstart[g]), 1.0f);
  GA[i] = (_Float16)(gsum[i] * gi);
}

extern "C" void kernel_launch(void* const* d_in, const int* in_sizes, int n_in,
                              void* d_out, int out_size, void* d_ws, size_t ws_size,
                              hipStream_t stream) {
  const float* x   = (const float*)d_in[0];
  const int* ei    = (const int*)d_in[1];
  const int* batch = (const int*)d_in[2];
  const float* W1 = (const float*)d_in[3];
  const float* b1 = (const float*)d_in[4];
  const float* W2 = (const float*)d_in[5];
  const float* b2 = (const float*)d_in[6];
  const float* W3 = (const float*)d_in[7];
  const float* b3 = (const float*)d_in[8];
  const float* fW1 = (const float*)d_in[9];
  const float* fb1 = (const float*)d_in[10];
  const float* fW2 = (const float*)d_in[11];
  const float* fb2 = (const float*)d_in[12];
  float* out = (float*)d_out;

  const int Nn = N_NODES, E = N_EDGES, G = N_GRAPHS;
  const int* src = ei;
  const int* dst = ei + E;

  // ---- workspace layout (~400 MB): A/B ping-pong stride 168 + gsum f32 ----
  _Float16* A = (_Float16*)d_ws;                          // [N,168]
  _Float16* B = A + (size_t)Nn * 168;                     // [N,168]
  _Float16* GA = B + (size_t)Nn * 168;                    // [G,320] chunk80 f16
  float*    gsum = (float*)(GA + (size_t)G * 320);        // [G,320] f32
  _Float16* W1T   = (_Float16*)(gsum + (size_t)G * 320);  // [96][104]
  _Float16* W2T   = W1T + 96 * 104;                       // [160][104]
  _Float16* W3T   = W2T + 160 * 104;                      // [320][168] chunk80
  _Float16* fW1T  = W3T + 320 * 168;                      // [1040][320] chunk80
  _Float16* fW2T  = fW1T + (size_t)1040 * 320;            // [160][1056]
  float* dinv     = (float*)(fW2T + (size_t)160 * 1056);  // [N]
  int* rowptr     = (int*)(dinv + Nn);                    // [N+1]
  int* cur        = rowptr + Nn + 1;                      // [N]
  int* ssrc       = cur + Nn;                             // [E]
  int* partials   = ssrc + E;                             // [512]
  int* gstart     = partials + 512;                       // [G+1]
  int4* ell = (int4*)(((uintptr_t)(gstart + G + 1) + 15) & ~(uintptr_t)15);  // [N]

  _Float16* Xh = A;      // [N,104]
  _Float16* Z1 = B;      // [N,104]
  _Float16* H1 = A;      // [N,104]
  _Float16* Z2 = B;      // [N,104]
  _Float16* H2 = A;      // [N,168]
  _Float16* Z3 = B;      // [N,168]
  _Float16* fc1 = A;     // [G,1056] (A dead after aggregateZ(H2->Z3))

  dim3 blk(256);
  const int gN13 = (int)(((unsigned)Nn * 13u + 255u) / 256u);
  const int gN20 = (int)(((unsigned)Nn * 20u + 255u) / 256u);
  const dim3 oneGrid(1, (Nn + 63) / 64);    // 7813
  const dim3 pairGrid(2, (Nn + 63) / 64);
  const dim3 quadGrid(4, (Nn + 63) / 64);
  const int NB = (Nn + 1023) / 1024;  // 489

  // ---- CSR build + ELL + graph starts ----
  fill_u32<<<(Nn + 255) / 256, blk, 0, stream>>>((unsigned*)cur, 0u, Nn);
  hist_dst<<<(E + 255) / 256, blk, 0, stream>>>(dst, cur, E);
  scanA<<<NB, blk, 0, stream>>>(cur, rowptr, partials, Nn);
  scanB<<<1, 512, 0, stream>>>(partials, NB);
  scanC<<<(Nn + 255) / 256, blk, 0, stream>>>(rowptr, partials, cur, Nn, E);
  dinv_k<<<(Nn + 255) / 256, blk, 0, stream>>>(rowptr, dinv, Nn);
  bucket<<<(E + 255) / 256, blk, 0, stream>>>(src, dst, cur, ssrc, E);
  ell_build<<<(Nn + 255) / 256, blk, 0, stream>>>(rowptr, ssrc, ell, Nn);
  graph_starts<<<(Nn + 256) / 256, blk, 0, stream>>>(batch, gstart, Nn);

  // ---- fp16 transposed weights (zero-padded rows/cols) ----
  wt_conv<0><<<(96 * 104 + 255) / 256, blk, 0, stream>>>(W1, W1T, 78, 78, 78, 96, 104, 96 * 104);
  wt_conv<0><<<(160 * 104 + 255) / 256, blk, 0, stream>>>(W2, W2T, 78, 156, 156, 96, 104, 160 * 104);
  wt_conv<80><<<(320 * 168 + 255) / 256, blk, 0, stream>>>(W3, W3T, 156, 312, 312, 160, 168, 320 * 168);
  wt_conv<80><<<(1040 * 320 + 255) / 256, blk, 0, stream>>>(fW1, fW1T, 312, 1024, 1024, 320, 320, 1040 * 320);
  wt_conv<0><<<(160 * 1056 + 255) / 256, blk, 0, stream>>>(fW2, fW2T, 1024, 128, 128, 1056, 1056, 160 * 1056);

  // ---- zero gsum; x -> f16 X' = D X [N,104] ----
  fill_u32<<<(G * 320 + 255) / 256, blk, 0, stream>>>((unsigned*)gsum, 0u, G * 320);
  xconv<<<(int)(((unsigned)Nn * 52u + 255u) / 256u), blk, 0, stream>>>(x, dinv, Xh);

  // ---- layer 1: Z1 = D(I+A)X' ; H1 = relu(Z1 W1 + b1) * dinv ----
  aggregateZ<104, 13><<<gN13, blk, 0, stream>>>(Xh, ell, rowptr, ssrc, dinv, Z1, 104);
  gemm_lds<96, 104, 3, 0><<<oneGrid, blk, 0, stream>>>(Z1, W1T, H1, dinv, b1, Nn, 104, nullptr, nullptr);

  // ---- layer 2: Z2 = D(I+A)H1 ; H2 = relu(Z2 W2 + b2) * dinv (2 planes) ----
  aggregateZ<104, 13><<<gN13, blk, 0, stream>>>(H1, ell, rowptr, ssrc, dinv, Z2, 104);
  gemm_lds<96, 104, 3, 0><<<pairGrid, blk, 0, stream>>>(Z2, W2T, H2, dinv, b2, Nn, 168, nullptr, nullptr);

  // ---- layer 3: Z3 = D(I+A)H2 ; ONE fused gemm+pool over 4 planes ----
  aggregateZ<168, 20><<<gN20, blk, 0, stream>>>(H2, ell, rowptr, ssrc, dinv, Z3, 168);
  gemm_lds<160, 168, 1, 1><<<quadGrid, blk, 0, stream>>>(Z3, W3T, nullptr, nullptr, b3, Nn, 0, batch, gsum);

  // ---- mean scale -> GA f16 ----
  ga_scale<<<(G * 320 + 255) / 256, blk, 0, stream>>>(gsum, gstart, GA);

  // ---- FC1: relu(GA @ fW1 + fb1) -> fc1 f16 (B staged in 50 KB LDS) ----
  {
    dim3 g((1024 + 79) / 80, (G + 127) / 128);  // 13 x 157
    gemm_direct<320, 1, 1><<<g, blk, 0, stream>>>(GA, fW1T, fc1, fb1, G, 1024, 1056);
  }
  // ---- FC2: out = fc1 @ fW2 + fb2 (f32) ----
  {
    dim3 g((128 + 79) / 80, (G + 127) / 128);  // 2 x 157
    gemm_direct<1056, 2, 0><<<g, blk, 0, stream>>>(fc1, fW2T, out, fb2, G, 128, 128);
  }
}

// Round 18
// 1019.235 us; speedup vs baseline: 1.1364x; 1.1364x over previous
//
#include <hip/hip_runtime.h>
#include <hip/hip_fp16.h>

#define N_NODES 500000
#define N_EDGES 1000000
#define N_GRAPHS 20000

typedef _Float16 f16x8 __attribute__((ext_vector_type(8)));
typedef float f32x4 __attribute__((ext_vector_type(4)));

__global__ __launch_bounds__(256) void fill_u32(unsigned* p, unsigned v, int n) {
  int i = blockIdx.x * 256 + threadIdx.x;
  if (i < n) p[i] = v;
}

__global__ __launch_bounds__(256) void hist_dst(const int* __restrict__ dst, int* cnt, int e) {
  int i = blockIdx.x * 256 + threadIdx.x;
  if (i < e) atomicAdd(&cnt[dst[i]], 1);
}

// ---- 2-level exclusive scan over deg[N] (1024 elems/block) ----
__global__ __launch_bounds__(256) void scanA(const int* __restrict__ deg, int* __restrict__ loc,
                                             int* __restrict__ partials, int n) {
  __shared__ int ts[256];
  int b = blockIdx.x, t = threadIdx.x;
  int base = b * 1024 + t * 4;
  int v[4], s = 0;
#pragma unroll
  for (int j = 0; j < 4; ++j) {
    v[j] = (base + j < n) ? deg[base + j] : 0;
    s += v[j];
  }
  ts[t] = s;
  __syncthreads();
  for (int off = 1; off < 256; off <<= 1) {
    int x = (t >= off) ? ts[t - off] : 0;
    __syncthreads();
    ts[t] += x;
    __syncthreads();
  }
  if (t == 255) partials[b] = ts[255];
  int run = ts[t] - s;  // exclusive
#pragma unroll
  for (int j = 0; j < 4; ++j) {
    if (base + j < n) loc[base + j] = run;
    run += v[j];
  }
}

__global__ __launch_bounds__(512) void scanB(int* partials, int nb) {
  __shared__ int s[512];
  int t = threadIdx.x;
  s[t] = (t < nb) ? partials[t] : 0;
  __syncthreads();
  if (t == 0) {
    int run = 0;
    for (int i = 0; i < nb; ++i) { int v = s[i]; s[i] = run; run += v; }
  }
  __syncthreads();
  if (t < nb) partials[t] = s[t];
}

__global__ __launch_bounds__(256) void scanC(int* __restrict__ rowptr, const int* __restrict__ partials,
                                             int* __restrict__ cur, int n, int e) {
  int i = blockIdx.x * 256 + threadIdx.x;
  if (i < n) {
    int v = rowptr[i] + partials[i >> 10];
    rowptr[i] = v;
    cur[i] = v;
  }
  if (i == 0) rowptr[n] = e;
}

__global__ __launch_bounds__(256) void dinv_k(const int* __restrict__ rowptr, float* dinv, int n) {
  int i = blockIdx.x * 256 + threadIdx.x;
  if (i < n) dinv[i] = rsqrtf(1.0f + (float)(rowptr[i + 1] - rowptr[i]));
}

__global__ __launch_bounds__(256) void bucket(const int* __restrict__ src, const int* __restrict__ dst,
                                              int* __restrict__ cur, int* __restrict__ ssrc, int e) {
  int i = blockIdx.x * 256 + threadIdx.x;
  if (i < e) ssrc[atomicAdd(&cur[dst[i]], 1)] = src[i];
}

// ell[n] = {deg, s0, s1, s2}
__global__ __launch_bounds__(256) void ell_build(const int* __restrict__ rowptr,
                                                 const int* __restrict__ ssrc,
                                                 int4* __restrict__ ell, int n) {
  int i = blockIdx.x * 256 + threadIdx.x;
  if (i >= n) return;
  int r0 = rowptr[i], r1 = rowptr[i + 1];
  int deg = r1 - r0;
  int4 e;
  e.x = deg;
  e.y = (deg > 0) ? ssrc[r0] : 0;
  e.z = (deg > 1) ? ssrc[r0 + 1] : 0;
  e.w = (deg > 2) ? ssrc[r0 + 2] : 0;
  ell[i] = e;
}

// gstart[g] = first node index of graph g (batch sorted); gstart[G] = N
__global__ __launch_bounds__(256) void graph_starts(const int* __restrict__ batch,
                                                    int* __restrict__ gstart, int n) {
  int i = blockIdx.x * 256 + threadIdx.x;
  if (i < n) {
    int b = batch[i];
    int bp = (i == 0) ? -1 : batch[i - 1];
    for (int g = bp + 1; g <= b; ++g) gstart[g] = i;
  } else if (i == n) {
    int bl = batch[n - 1];
    for (int g = bl + 1; g <= N_GRAPHS; ++g) gstart[g] = n;
  }
}

// WT[c][k'] = f16(W[k][c]), rows stride STRIDE (zero beyond KPL / Nout).
// CW>0: chunk layout, k = 78*(k'/CW) + k'%CW, valid (k'%CW)<78.
template <int CW>
__global__ __launch_bounds__(256) void wt_conv(const float* __restrict__ W, _Float16* __restrict__ WT,
                                               int K, int Nout, int ldw, int KPL, int STRIDE, int total) {
  int i = blockIdx.x * 256 + threadIdx.x;
  if (i >= total) return;
  int c = i / STRIDE, kp = i - c * STRIDE;
  int k = kp; bool valid = kp < KPL;
  if (CW) { int blk = kp / CW, r = kp - blk * CW; k = blk * 78 + r; valid = valid && (r < 78) && (k < K); }
  else { valid = valid && (kp < K); }
  WT[i] = (valid && c < Nout) ? (_Float16)W[(size_t)k * ldw + c] : (_Float16)0.f;
}

// Xh[n, 0:104] = f16(x[n, 0:78] * dinv[n]), zero pad to 104
__global__ __launch_bounds__(256) void xconv(const float* __restrict__ xin,
                                             const float* __restrict__ dinv,
                                             _Float16* __restrict__ Xh) {
  unsigned idx = blockIdx.x * 256u + threadIdx.x;
  if (idx >= (unsigned)N_NODES * 52u) return;
  unsigned n = idx / 52u, c2 = idx - n * 52u;
  __half2 h = __floats2half2_rn(0.f, 0.f);
  if (c2 < 39u) {
    float di = dinv[n];
    float2 v = *reinterpret_cast<const float2*>(xin + (size_t)n * 78 + 2 * c2);
    h = __floats2half2_rn(v.x * di, v.y * di);
  }
  *reinterpret_cast<__half2*>((__half*)Xh + (size_t)n * 104 + 2 * c2) = h;
}

__device__ __forceinline__ void async16(const void* g, void* l) {
  __builtin_amdgcn_global_load_lds(
      (const __attribute__((address_space(1))) void*)g,
      (__attribute__((address_space(3))) void*)l, 16, 0, 0);
}

// Async-LDS MFMA GEMM. BM=64 rows, 4 waves x 16 rows, plane = 78 output cols.
// A and B staged via global_load_lds (zero VGPR cost, all loads in flight),
// single barrier, then pure ds_read_b128 + MFMA. Strides 104/168 f16 give
// 2-way LDS bank aliasing (free). blockIdx.x = plane: wt += x*78*STRIDE,
// out += x*80, bias += x*78; Nout=78 per plane.
// OUT_MODE 1: relu(v+b) -> f16 ; 3: relu(v+b)*rs[row] -> f16
template <int KPL, int STRIDE, int OUT_MODE>
__global__ __launch_bounds__(256) void gemm_lds(
    const _Float16* __restrict__ in, const _Float16* __restrict__ WT,
    _Float16* __restrict__ outp, const float* __restrict__ rs,
    const float* __restrict__ bo, int M, int LDO) {
  constexpr int NS = KPL / 32;
  constexpr int SB = STRIDE * 2;                 // row bytes
  constexpr int CA = (64 * SB) / 1024;           // A chunks
  constexpr int CB = (80 * SB + 1023) / 1024;    // B chunks (last reads slack)
  __shared__ __align__(16) _Float16 As[64 * STRIDE];
  __shared__ __align__(16) _Float16 Bs[CB * 512];
  const int tid = threadIdx.x;
  const int lane = tid & 63;
  const int wid = tid >> 6;
  const int row0 = blockIdx.y * 64;
  const _Float16* wt = WT + (size_t)(blockIdx.x * 78) * STRIDE;
  _Float16* out = outp + (size_t)blockIdx.x * 80;
  const float* bop = bo + blockIdx.x * 78;

  // ---- async stage A (64 rows) and B (80 weight rows), linear copies ----
  const char* ab = (const char*)in + (size_t)row0 * SB;
  for (int c = wid; c < CA; c += 4)
    async16(ab + (size_t)c * 1024 + lane * 16, (char*)As + c * 1024);
  const char* bb = (const char*)wt;
  for (int c = wid; c < CB; c += 4)
    async16(bb + (size_t)c * 1024 + lane * 16, (char*)Bs + c * 1024);
  __syncthreads();  // drains vmcnt before barrier

  const int r16 = lane & 15, q = lane >> 4;
  const f32x4 z4 = {0.f, 0.f, 0.f, 0.f};
  f32x4 acc[5];
#pragma unroll
  for (int nf = 0; nf < 5; ++nf) acc[nf] = z4;

#pragma unroll
  for (int s = 0; s < NS; ++s) {
    f16x8 af = *reinterpret_cast<const f16x8*>(&As[(wid * 16 + r16) * STRIDE + s * 32 + q * 8]);
#pragma unroll
    for (int nf = 0; nf < 5; ++nf) {
      f16x8 bf = *reinterpret_cast<const f16x8*>(&Bs[(nf * 16 + r16) * STRIDE + s * 32 + q * 8]);
      acc[nf] = __builtin_amdgcn_mfma_f32_16x16x32_f16(af, bf, acc[nf], 0, 0, 0);
    }
  }

  // ---- epilogue: acc -> LDS [64][80] (zero pads) -> coalesced uint4 stores ----
  __syncthreads();
  _Float16* Os = As;
#pragma unroll
  for (int j = 0; j < 4; ++j) {
    int rl = wid * 16 + q * 4 + j;
    int gr = row0 + rl;
    float sc = (OUT_MODE == 3 && gr < M) ? rs[gr] : 1.f;
#pragma unroll
    for (int nf = 0; nf < 5; ++nf) {
      int cl = nf * 16 + r16;
      float v = 0.f;
      if (cl < 78) {
        v = fmaxf(acc[nf][j] + bop[cl], 0.f);
        if (OUT_MODE == 3) v *= sc;
      }
      Os[rl * 80 + cl] = (_Float16)v;
    }
  }
  __syncthreads();
  for (int i = tid; i < 640; i += 256) {
    int rl = i / 10, u = i - rl * 10;
    int gr = row0 + rl;
    if (gr < M)
      *reinterpret_cast<uint4*>(&out[(size_t)gr * LDO + u * 8]) =
          *reinterpret_cast<const uint4*>(&Os[rl * 80 + u * 8]);
  }
}

// Direct-register MFMA GEMM (FC layers). Tile 128x80, 4 waves.
// BLDS=1: B staged fragment-linear in LDS. TSTORE: coalesced f16 store via LDS.
// OUT_MODE 1: relu(v+b) -> f16 ; 2: v+b -> f32
template <int KP, int OUT_MODE, int BLDS>
__global__ __launch_bounds__(256) void gemm_direct(
    const _Float16* __restrict__ in, const _Float16* __restrict__ WT,
    void* __restrict__ outp, const float* __restrict__ bo,
    int M, int Nout, int LDO) {
  constexpr int NS = KP / 32;
  constexpr bool TSTORE = (BLDS != 0) && (OUT_MODE != 2);
  constexpr int BS_BYTES = BLDS ? 5 * NS * 64 * 16 : 16;
  constexpr int SM_BYTES = TSTORE ? (BS_BYTES > 20480 ? BS_BYTES : 20480) : BS_BYTES;
  __shared__ __align__(16) char smem[SM_BYTES];
  _Float16* Bs = (_Float16*)smem;
  const int tid = threadIdx.x;
  const int lane = tid & 63;
  const int wid = tid >> 6;
  const int row0 = blockIdx.y * 128;
  const int col0 = blockIdx.x * 80;
  const _Float16* wt = WT + (size_t)col0 * KP;
  _Float16* out16 = (_Float16*)outp;
  float* out32 = (float*)outp;
  const int koff = (lane >> 4) * 8;
  const int gr0 = row0 + wid * 32 + (lane & 15);
  const bool v0 = gr0 < M, v1 = (gr0 + 16) < M;
  const _Float16* a0 = in + (size_t)gr0 * KP + koff;
  const _Float16* a1 = a0 + (size_t)16 * KP;
  const _Float16* bp = wt + (size_t)(lane & 15) * KP + koff;

  if (BLDS) {
    for (int i = tid; i < 5 * NS * 64; i += 256) {
      int l = i & 63;
      int nf = (i >> 6) % 5;
      int s = i / 320;
      int r = nf * 16 + (l & 15);
      int k = s * 32 + ((l >> 4) << 3);
      *reinterpret_cast<uint4*>(&Bs[(size_t)i * 8]) =
          *reinterpret_cast<const uint4*>(wt + (size_t)r * KP + k);
    }
    __syncthreads();
  }

  const f16x8 zf = {0, 0, 0, 0, 0, 0, 0, 0};
  const f32x4 z4 = {0.f, 0.f, 0.f, 0.f};
  f32x4 acc[2][5];
#pragma unroll
  for (int a = 0; a < 2; ++a)
#pragma unroll
    for (int b = 0; b < 5; ++b) acc[a][b] = z4;

#pragma unroll
  for (int s = 0; s < NS; ++s) {
    f16x8 af0 = v0 ? *reinterpret_cast<const f16x8*>(a0 + s * 32) : zf;
    f16x8 af1 = v1 ? *reinterpret_cast<const f16x8*>(a1 + s * 32) : zf;
    f16x8 bf[5];
#pragma unroll
    for (int nf = 0; nf < 5; ++nf) {
      if (BLDS)
        bf[nf] = *reinterpret_cast<const f16x8*>(&Bs[((size_t)(s * 5 + nf) * 64 + lane) * 8]);
      else
        bf[nf] = *reinterpret_cast<const f16x8*>(bp + (size_t)nf * 16 * KP + s * 32);
    }
#pragma unroll
    for (int nf = 0; nf < 5; ++nf) {
      acc[0][nf] = __builtin_amdgcn_mfma_f32_16x16x32_f16(af0, bf[nf], acc[0][nf], 0, 0, 0);
      acc[1][nf] = __builtin_amdgcn_mfma_f32_16x16x32_f16(af1, bf[nf], acc[1][nf], 0, 0, 0);
    }
  }

  if constexpr (TSTORE) {
    __syncthreads();
    _Float16* Os = (_Float16*)smem;
#pragma unroll
    for (int rf = 0; rf < 2; ++rf) {
#pragma unroll
      for (int j = 0; j < 4; ++j) {
        int rl = wid * 32 + rf * 16 + (lane >> 4) * 4 + j;
#pragma unroll
        for (int nf = 0; nf < 5; ++nf) {
          int cl = nf * 16 + (lane & 15);
          int oc = col0 + cl;
          float r = 0.f;
          if (oc < Nout) r = fmaxf(acc[rf][nf][j] + bo[oc], 0.f);
          Os[rl * 80 + cl] = (_Float16)r;
        }
      }
    }
    __syncthreads();
    for (int i = tid; i < 1280; i += 256) {
      int rl = i / 10, u = i - rl * 10;
      int gr = row0 + rl;
      if (gr < M)
        *reinterpret_cast<uint4*>(&out16[(size_t)gr * LDO + col0 + u * 8]) =
            *reinterpret_cast<const uint4*>(&Os[rl * 80 + u * 8]);
    }
  } else {
#pragma unroll
    for (int rf = 0; rf < 2; ++rf) {
#pragma unroll
      for (int j = 0; j < 4; ++j) {
        int gr = row0 + wid * 32 + rf * 16 + (lane >> 4) * 4 + j;
        if (gr >= M) continue;
#pragma unroll
        for (int nf = 0; nf < 5; ++nf) {
          int oc = col0 + nf * 16 + (lane & 15);
          if (oc >= Nout) continue;
          float v = acc[rf][nf][j];
          if (OUT_MODE == 1) out16[(size_t)gr * LDO + oc] = (_Float16)fmaxf(v + bo[oc], 0.f);
          else out32[(size_t)gr * LDO + oc] = v + bo[oc];
        }
      }
    }
  }
}

__device__ inline void acc8(float* a, uint4 v) {
  const __half2* h = reinterpret_cast<const __half2*>(&v);
#pragma unroll
  for (int j = 0; j < 4; ++j) {
    float2 f = __half22float2(h[j]);
    a[2 * j] += f.x;
    a[2 * j + 1] += f.y;
  }
}

// segment-sum gather; rows stride LDI f16 from hbase
template <int LDI>
__device__ inline void gather_sumT(float* a, const _Float16* hbase, unsigned n,
                                   const int4* __restrict__ ell,
                                   const int* __restrict__ rowptr,
                                   const int* __restrict__ ssrc) {
  int4 e = ell[n];
  const int deg = e.x;
  uint4 sv = *reinterpret_cast<const uint4*>(hbase + (size_t)n * LDI);
  uint4 g0, g1, g2;
  if (deg > 0) g0 = *reinterpret_cast<const uint4*>(hbase + (size_t)e.y * LDI);
  if (deg > 1) g1 = *reinterpret_cast<const uint4*>(hbase + (size_t)e.z * LDI);
  if (deg > 2) g2 = *reinterpret_cast<const uint4*>(hbase + (size_t)e.w * LDI);
  {
    const __half2* h = reinterpret_cast<const __half2*>(&sv);
#pragma unroll
    for (int j = 0; j < 4; ++j) {
      float2 f = __half22float2(h[j]);
      a[2 * j] = f.x;
      a[2 * j + 1] = f.y;
    }
  }
  if (deg > 0) acc8(a, g0);
  if (deg > 1) acc8(a, g1);
  if (deg > 2) acc8(a, g2);
  if (deg > 3) {
    int r = rowptr[n] + 3, r1 = r + deg - 3;
    for (; r + 2 <= r1; r += 2) {
      uint4 va = *reinterpret_cast<const uint4*>(hbase + (size_t)ssrc[r] * LDI);
      uint4 vb = *reinterpret_cast<const uint4*>(hbase + (size_t)ssrc[r + 1] * LDI);
      acc8(a, va);
      acc8(a, vb);
    }
    if (r < r1) {
      uint4 va = *reinterpret_cast<const uint4*>(hbase + (size_t)ssrc[r] * LDI);
      acc8(a, va);
    }
  }
}

// Input-side aggregation: Z[n] = f16(dinv[n] * (in[n] + Σ_seg in[ssrc]))
// NSUB covers only the USEFUL columns (pads beyond NSUB*8 are never read with
// nonzero weights, so they may hold stale finite data).
template <int LDI, int NSUB>
__global__ __launch_bounds__(256) void aggregateZ(
    const _Float16* __restrict__ in, const int4* __restrict__ ell,
    const int* __restrict__ rowptr, const int* __restrict__ ssrc,
    const float* __restrict__ dinv, _Float16* __restrict__ outZ, int ldo) {
  unsigned idx = blockIdx.x * 256u + threadIdx.x;
  if (idx >= (unsigned)N_NODES * NSUB) return;
  unsigned n = idx / NSUB, sub = idx - n * NSUB;
  float a[8];
  gather_sumT<LDI>(a, in + sub * 8u, n, ell, rowptr, ssrc);
  float di = dinv[n];
  _Float16 ov[8];
#pragma unroll
  for (int j = 0; j < 8; ++j) ov[j] = (_Float16)(di * a[j]);
  *reinterpret_cast<uint4*>(outZ + (size_t)n * ldo + sub * 8u) =
      *reinterpret_cast<const uint4*>(ov);
}

// Mean-pool over contiguous node range, 16B/thread (10 threads/graph):
// GA[g*320 + coffGA + q*8..] = (1/cnt) Σ_n in[n*168 + inOff + q*8..]
__global__ __launch_bounds__(256) void pool_seq(
    const _Float16* __restrict__ in, const int* __restrict__ gstart,
    _Float16* __restrict__ GA, int inOff, int coffGA) {
  unsigned idx = blockIdx.x * 256u + threadIdx.x;
  if (idx >= (unsigned)N_GRAPHS * 10u) return;
  unsigned g = idx / 10u, q = idx - g * 10u;
  int n0 = gstart[g], n1 = gstart[g + 1];
  const _Float16* base = in + inOff + q * 8;
  float a[8] = {0.f, 0.f, 0.f, 0.f, 0.f, 0.f, 0.f, 0.f};
  float b2[8] = {0.f, 0.f, 0.f, 0.f, 0.f, 0.f, 0.f, 0.f};
  int n = n0;
  for (; n + 2 <= n1; n += 2) {
    uint4 va = *reinterpret_cast<const uint4*>(base + (size_t)n * 168);
    uint4 vb = *reinterpret_cast<const uint4*>(base + (size_t)(n + 1) * 168);
    acc8(a, va);
    acc8(b2, vb);
  }
  if (n < n1) {
    uint4 va = *reinterpret_cast<const uint4*>(base + (size_t)n * 168);
    acc8(a, va);
  }
  float gi = 1.0f / fmaxf((float)(n1 - n0), 1.0f);
  _Float16 ov[8];
#pragma unroll
  for (int j = 0; j < 8; ++j) ov[j] = (_Float16)((a[j] + b2[j]) * gi);
  *reinterpret_cast<uint4*>(GA + (size_t)g * 320 + coffGA + q * 8) =
      *reinterpret_cast<const uint4*>(ov);
}

extern "C" void kernel_launch(void* const* d_in, const int* in_sizes, int n_in,
                              void* d_out, int out_size, void* d_ws, size_t ws_size,
                              hipStream_t stream) {
  const float* x   = (const float*)d_in[0];
  const int* ei    = (const int*)d_in[1];
  const int* batch = (const int*)d_in[2];
  const float* W1 = (const float*)d_in[3];
  const float* b1 = (const float*)d_in[4];
  const float* W2 = (const float*)d_in[5];
  const float* b2 = (const float*)d_in[6];
  const float* W3 = (const float*)d_in[7];
  const float* b3 = (const float*)d_in[8];
  const float* fW1 = (const float*)d_in[9];
  const float* fb1 = (const float*)d_in[10];
  const float* fW2 = (const float*)d_in[11];
  const float* fb2 = (const float*)d_in[12];
  float* out = (float*)d_out;

  const int Nn = N_NODES, E = N_EDGES, G = N_GRAPHS;
  const int* src = ei;
  const int* dst = ei + E;

  // ---- workspace layout (~370 MB): A/B ping-pong, stride 168 ----
  _Float16* A = (_Float16*)d_ws;                          // [N,168]
  _Float16* B = A + (size_t)Nn * 168;                     // [N,168]
  _Float16* GA = B + (size_t)Nn * 168;                    // [G,320] chunk80
  _Float16* W1T   = GA + (size_t)G * 320;                 // [96][104]
  _Float16* W2T   = W1T + 96 * 104;                       // [160][104]
  _Float16* W3T   = W2T + 160 * 104;                      // [320][168] chunk80
  _Float16* fW1T  = W3T + 320 * 168;                      // [1040][320] chunk80
  _Float16* fW2T  = fW1T + (size_t)1040 * 320;            // [160][1056]
  float* dinv     = (float*)(fW2T + (size_t)160 * 1056);  // [N]
  int* rowptr     = (int*)(dinv + Nn);                    // [N+1]
  int* cur        = rowptr + Nn + 1;                      // [N]
  int* ssrc       = cur + Nn;                             // [E]
  int* partials   = ssrc + E;                             // [512]
  int* gstart     = partials + 512;                       // [G+1]
  int4* ell = (int4*)(((uintptr_t)(gstart + G + 1) + 15) & ~(uintptr_t)15);  // [N]

  _Float16* Xh = A;      // [N,104]
  _Float16* Z1 = B;      // [N,104]
  _Float16* H1 = A;      // [N,104]
  _Float16* Z2 = B;      // [N,104]
  _Float16* H2 = A;      // [N,168]
  _Float16* Z3 = B;      // [N,168]
  _Float16* O3 = A;      // [N,168] per L3 pass
  _Float16* fc1 = B;     // [G,1056]

  dim3 blk(256);
  const int gN10 = (int)(((unsigned)Nn * 10u + 255u) / 256u);
  const int gN20 = (int)(((unsigned)Nn * 20u + 255u) / 256u);
  const int gG10 = (int)(((unsigned)G * 10u + 255u) / 256u);
  const dim3 oneGrid(1, (Nn + 63) / 64);    // 7813
  const dim3 pairGrid(2, (Nn + 63) / 64);
  const int NB = (Nn + 1023) / 1024;  // 489

  // ---- CSR build + ELL + graph starts ----
  fill_u32<<<(Nn + 255) / 256, blk, 0, stream>>>((unsigned*)cur, 0u, Nn);
  hist_dst<<<(E + 255) / 256, blk, 0, stream>>>(dst, cur, E);
  scanA<<<NB, blk, 0, stream>>>(cur, rowptr, partials, Nn);
  scanB<<<1, 512, 0, stream>>>(partials, NB);
  scanC<<<(Nn + 255) / 256, blk, 0, stream>>>(rowptr, partials, cur, Nn, E);
  dinv_k<<<(Nn + 255) / 256, blk, 0, stream>>>(rowptr, dinv, Nn);
  bucket<<<(E + 255) / 256, blk, 0, stream>>>(src, dst, cur, ssrc, E);
  ell_build<<<(Nn + 255) / 256, blk, 0, stream>>>(rowptr, ssrc, ell, Nn);
  graph_starts<<<(Nn + 256) / 256, blk, 0, stream>>>(batch, gstart, Nn);

  // ---- fp16 transposed weights (zero-padded rows/cols) ----
  wt_conv<0><<<(96 * 104 + 255) / 256, blk, 0, stream>>>(W1, W1T, 78, 78, 78, 96, 104, 96 * 104);
  wt_conv<0><<<(160 * 104 + 255) / 256, blk, 0, stream>>>(W2, W2T, 78, 156, 156, 96, 104, 160 * 104);
  wt_conv<80><<<(320 * 168 + 255) / 256, blk, 0, stream>>>(W3, W3T, 156, 312, 312, 160, 168, 320 * 168);
  wt_conv<80><<<(1040 * 320 + 255) / 256, blk, 0, stream>>>(fW1, fW1T, 312, 1024, 1024, 320, 320, 1040 * 320);
  wt_conv<0><<<(160 * 1056 + 255) / 256, blk, 0, stream>>>(fW2, fW2T, 1024, 128, 128, 1056, 1056, 160 * 1056);

  // ---- x -> f16 X' = D X [N,104] (zero pad) ----
  xconv<<<(int)(((unsigned)Nn * 52u + 255u) / 256u), blk, 0, stream>>>(x, dinv, Xh);

  // ---- layer 1: Z1 = D(I+A)X' (80 cols) ; H1 = relu(Z1 W1 + b1) * dinv ----
  aggregateZ<104, 10><<<gN10, blk, 0, stream>>>(Xh, ell, rowptr, ssrc, dinv, Z1, 104);
  gemm_lds<96, 104, 3><<<oneGrid, blk, 0, stream>>>(Z1, W1T, H1, dinv, b1, Nn, 104);

  // ---- layer 2: Z2 = D(I+A)H1 (80 cols) ; H2 = relu(Z2 W2 + b2)*dinv (2 planes) ----
  aggregateZ<104, 10><<<gN10, blk, 0, stream>>>(H1, ell, rowptr, ssrc, dinv, Z2, 104);
  gemm_lds<96, 104, 3><<<pairGrid, blk, 0, stream>>>(Z2, W2T, H2, dinv, b2, Nn, 168);

  // ---- layer 3: Z3 = D(I+A)H2 (160 cols) ; 2 passes: O3 -> pools ----
  aggregateZ<168, 20><<<gN20, blk, 0, stream>>>(H2, ell, rowptr, ssrc, dinv, Z3, 168);
  for (int p = 0; p < 2; ++p) {
    gemm_lds<160, 168, 1><<<pairGrid, blk, 0, stream>>>(
        Z3, W3T + (size_t)(156 * p) * 168, O3, nullptr, b3 + 156 * p, Nn, 168);
    pool_seq<<<gG10, blk, 0, stream>>>(O3, gstart, GA, 0, (2 * p) * 80);
    pool_seq<<<gG10, blk, 0, stream>>>(O3, gstart, GA, 80, (2 * p + 1) * 80);
  }

  // ---- FC1: relu(GA @ fW1 + fb1) -> fc1 f16 (B staged in 50 KB LDS) ----
  {
    dim3 g((1024 + 79) / 80, (G + 127) / 128);  // 13 x 157
    gemm_direct<320, 1, 1><<<g, blk, 0, stream>>>(GA, fW1T, fc1, fb1, G, 1024, 1056);
  }
  // ---- FC2: out = fc1 @ fW2 + fb2 (f32) ----
  {
    dim3 g((128 + 79) / 80, (G + 127) / 128);  // 2 x 157
    gemm_direct<1056, 2, 0><<<g, blk, 0, stream>>>(fc1, fW2T, out, fb2, G, 128, 128);
  }
}

// Round 19
// 977.075 us; speedup vs baseline: 1.1854x; 1.0431x over previous
//
#include <hip/hip_runtime.h>
#include <hip/hip_fp16.h>

#define N_NODES 500000
#define N_EDGES 1000000
#define N_GRAPHS 20000

typedef _Float16 f16x8 __attribute__((ext_vector_type(8)));
typedef float f32x4 __attribute__((ext_vector_type(4)));

__global__ __launch_bounds__(256) void fill_u32(unsigned* p, unsigned v, int n) {
  int i = blockIdx.x * 256 + threadIdx.x;
  if (i < n) p[i] = v;
}

__global__ __launch_bounds__(256) void hist_dst(const int* __restrict__ dst, int* cnt, int e) {
  int i = blockIdx.x * 256 + threadIdx.x;
  if (i < e) atomicAdd(&cnt[dst[i]], 1);
}

// ---- 2-level exclusive scan over deg[N] (1024 elems/block) ----
__global__ __launch_bounds__(256) void scanA(const int* __restrict__ deg, int* __restrict__ loc,
                                             int* __restrict__ partials, int n) {
  __shared__ int ts[256];
  int b = blockIdx.x, t = threadIdx.x;
  int base = b * 1024 + t * 4;
  int v[4], s = 0;
#pragma unroll
  for (int j = 0; j < 4; ++j) {
    v[j] = (base + j < n) ? deg[base + j] : 0;
    s += v[j];
  }
  ts[t] = s;
  __syncthreads();
  for (int off = 1; off < 256; off <<= 1) {
    int x = (t >= off) ? ts[t - off] : 0;
    __syncthreads();
    ts[t] += x;
    __syncthreads();
  }
  if (t == 255) partials[b] = ts[255];
  int run = ts[t] - s;  // exclusive
#pragma unroll
  for (int j = 0; j < 4; ++j) {
    if (base + j < n) loc[base + j] = run;
    run += v[j];
  }
}

__global__ __launch_bounds__(512) void scanB(int* partials, int nb) {
  __shared__ int s[512];
  int t = threadIdx.x;
  s[t] = (t < nb) ? partials[t] : 0;
  __syncthreads();
  if (t == 0) {
    int run = 0;
    for (int i = 0; i < nb; ++i) { int v = s[i]; s[i] = run; run += v; }
  }
  __syncthreads();
  if (t < nb) partials[t] = s[t];
}

__global__ __launch_bounds__(256) void scanC(int* __restrict__ rowptr, const int* __restrict__ partials,
                                             int* __restrict__ cur, int n, int e) {
  int i = blockIdx.x * 256 + threadIdx.x;
  if (i < n) {
    int v = rowptr[i] + partials[i >> 10];
    rowptr[i] = v;
    cur[i] = v;
  }
  if (i == 0) rowptr[n] = e;
}

__global__ __launch_bounds__(256) void bucket(const int* __restrict__ src, const int* __restrict__ dst,
                                              int* __restrict__ cur, int* __restrict__ ssrc, int e) {
  int i = blockIdx.x * 256 + threadIdx.x;
  if (i < e) ssrc[atomicAdd(&cur[dst[i]], 1)] = src[i];
}

// fused: dinv = rsqrt(1+deg); ell[n] = {deg, s0, s1, s2}; gstart boundaries
__global__ __launch_bounds__(256) void finalize_graph(
    const int* __restrict__ rowptr, const int* __restrict__ ssrc,
    const int* __restrict__ batch, float* __restrict__ dinv,
    int4* __restrict__ ell, int* __restrict__ gstart, int n) {
  int i = blockIdx.x * 256 + threadIdx.x;
  if (i < n) {
    int r0 = rowptr[i], r1 = rowptr[i + 1];
    int deg = r1 - r0;
    dinv[i] = rsqrtf(1.0f + (float)deg);
    int4 e;
    e.x = deg;
    e.y = (deg > 0) ? ssrc[r0] : 0;
    e.z = (deg > 1) ? ssrc[r0 + 1] : 0;
    e.w = (deg > 2) ? ssrc[r0 + 2] : 0;
    ell[i] = e;
    int b = batch[i];
    int bp = (i == 0) ? -1 : batch[i - 1];
    for (int g = bp + 1; g <= b; ++g) gstart[g] = i;
  } else if (i == n) {
    int bl = batch[n - 1];
    for (int g = bl + 1; g <= N_GRAPHS; ++g) gstart[g] = n;
  }
}

// WT[c][k'] = f16(W[k][c]), rows stride STRIDE (zero beyond KPL / Nout).
// CW>0: chunk layout, k = 78*(k'/CW) + k'%CW, valid (k'%CW)<78.
template <int CW>
__global__ __launch_bounds__(256) void wt_conv(const float* __restrict__ W, _Float16* __restrict__ WT,
                                               int K, int Nout, int ldw, int KPL, int STRIDE, int total) {
  int i = blockIdx.x * 256 + threadIdx.x;
  if (i >= total) return;
  int c = i / STRIDE, kp = i - c * STRIDE;
  int k = kp; bool valid = kp < KPL;
  if (CW) { int blk = kp / CW, r = kp - blk * CW; k = blk * 78 + r; valid = valid && (r < 78) && (k < K); }
  else { valid = valid && (kp < K); }
  WT[i] = (valid && c < Nout) ? (_Float16)W[(size_t)k * ldw + c] : (_Float16)0.f;
}

// Xh[n, 0:104] = f16(x[n, 0:78] * dinv[n]), zero pad to 104
__global__ __launch_bounds__(256) void xconv(const float* __restrict__ xin,
                                             const float* __restrict__ dinv,
                                             _Float16* __restrict__ Xh) {
  unsigned idx = blockIdx.x * 256u + threadIdx.x;
  if (idx >= (unsigned)N_NODES * 52u) return;
  unsigned n = idx / 52u, c2 = idx - n * 52u;
  __half2 h = __floats2half2_rn(0.f, 0.f);
  if (c2 < 39u) {
    float di = dinv[n];
    float2 v = *reinterpret_cast<const float2*>(xin + (size_t)n * 78 + 2 * c2);
    h = __floats2half2_rn(v.x * di, v.y * di);
  }
  *reinterpret_cast<__half2*>((__half*)Xh + (size_t)n * 104 + 2 * c2) = h;
}

__device__ __forceinline__ void async16(const void* g, void* l) {
  __builtin_amdgcn_global_load_lds(
      (const __attribute__((address_space(1))) void*)g,
      (__attribute__((address_space(3))) void*)l, 16, 0, 0);
}

// Async-LDS MFMA GEMM. BM=64 rows, 4 waves x 16 rows, plane = 78 output cols.
// A and B staged via global_load_lds (zero VGPR cost, all loads in flight),
// single barrier, then pure ds_read_b128 + MFMA. Strides 104/168 f16 give
// 2-way LDS bank aliasing (free). blockIdx.x = plane: wt += x*78*STRIDE,
// out += x*80, bias += x*78; Nout=78 per plane.
// OUT_MODE 1: relu(v+b) -> f16 ; 3: relu(v+b)*rs[row] -> f16
template <int KPL, int STRIDE, int OUT_MODE>
__global__ __launch_bounds__(256) void gemm_lds(
    const _Float16* __restrict__ in, const _Float16* __restrict__ WT,
    _Float16* __restrict__ outp, const float* __restrict__ rs,
    const float* __restrict__ bo, int M, int LDO) {
  constexpr int NS = KPL / 32;
  constexpr int SB = STRIDE * 2;                 // row bytes
  constexpr int CA = (64 * SB) / 1024;           // A chunks
  constexpr int CB = (80 * SB + 1023) / 1024;    // B chunks (last reads slack)
  __shared__ __align__(16) _Float16 As[64 * STRIDE];
  __shared__ __align__(16) _Float16 Bs[CB * 512];
  const int tid = threadIdx.x;
  const int lane = tid & 63;
  const int wid = tid >> 6;
  const int row0 = blockIdx.y * 64;
  const _Float16* wt = WT + (size_t)(blockIdx.x * 78) * STRIDE;
  _Float16* out = outp + (size_t)blockIdx.x * 80;
  const float* bop = bo + blockIdx.x * 78;

  // ---- async stage A (64 rows) and B (80 weight rows), linear copies ----
  const char* ab = (const char*)in + (size_t)row0 * SB;
  for (int c = wid; c < CA; c += 4)
    async16(ab + (size_t)c * 1024 + lane * 16, (char*)As + c * 1024);
  const char* bb = (const char*)wt;
  for (int c = wid; c < CB; c += 4)
    async16(bb + (size_t)c * 1024 + lane * 16, (char*)Bs + c * 1024);
  __syncthreads();  // drains vmcnt before barrier

  const int r16 = lane & 15, q = lane >> 4;
  const f32x4 z4 = {0.f, 0.f, 0.f, 0.f};
  f32x4 acc[5];
#pragma unroll
  for (int nf = 0; nf < 5; ++nf) acc[nf] = z4;

#pragma unroll
  for (int s = 0; s < NS; ++s) {
    f16x8 af = *reinterpret_cast<const f16x8*>(&As[(wid * 16 + r16) * STRIDE + s * 32 + q * 8]);
#pragma unroll
    for (int nf = 0; nf < 5; ++nf) {
      f16x8 bf = *reinterpret_cast<const f16x8*>(&Bs[(nf * 16 + r16) * STRIDE + s * 32 + q * 8]);
      acc[nf] = __builtin_amdgcn_mfma_f32_16x16x32_f16(af, bf, acc[nf], 0, 0, 0);
    }
  }

  // ---- epilogue: acc -> LDS [64][80] (zero pads) -> coalesced uint4 stores ----
  __syncthreads();
  _Float16* Os = As;
#pragma unroll
  for (int j = 0; j < 4; ++j) {
    int rl = wid * 16 + q * 4 + j;
    int gr = row0 + rl;
    float sc = (OUT_MODE == 3 && gr < M) ? rs[gr] : 1.f;
#pragma unroll
    for (int nf = 0; nf < 5; ++nf) {
      int cl = nf * 16 + r16;
      float v = 0.f;
      if (cl < 78) {
        v = fmaxf(acc[nf][j] + bop[cl], 0.f);
        if (OUT_MODE == 3) v *= sc;
      }
      Os[rl * 80 + cl] = (_Float16)v;
    }
  }
  __syncthreads();
  for (int i = tid; i < 640; i += 256) {
    int rl = i / 10, u = i - rl * 10;
    int gr = row0 + rl;
    if (gr < M)
      *reinterpret_cast<uint4*>(&out[(size_t)gr * LDO + u * 8]) =
          *reinterpret_cast<const uint4*>(&Os[rl * 80 + u * 8]);
  }
}

// Direct-register MFMA GEMM (FC layers). Tile 128x80, 4 waves.
// BLDS=1: B staged fragment-linear in LDS. TSTORE: coalesced f16 store via LDS.
// OUT_MODE 1: relu(v+b) -> f16 ; 2: v+b -> f32
template <int KP, int OUT_MODE, int BLDS>
__global__ __launch_bounds__(256) void gemm_direct(
    const _Float16* __restrict__ in, const _Float16* __restrict__ WT,
    void* __restrict__ outp, const float* __restrict__ bo,
    int M, int Nout, int LDO) {
  constexpr int NS = KP / 32;
  constexpr bool TSTORE = (BLDS != 0) && (OUT_MODE != 2);
  constexpr int BS_BYTES = BLDS ? 5 * NS * 64 * 16 : 16;
  constexpr int SM_BYTES = TSTORE ? (BS_BYTES > 20480 ? BS_BYTES : 20480) : BS_BYTES;
  __shared__ __align__(16) char smem[SM_BYTES];
  _Float16* Bs = (_Float16*)smem;
  const int tid = threadIdx.x;
  const int lane = tid & 63;
  const int wid = tid >> 6;
  const int row0 = blockIdx.y * 128;
  const int col0 = blockIdx.x * 80;
  const _Float16* wt = WT + (size_t)col0 * KP;
  _Float16* out16 = (_Float16*)outp;
  float* out32 = (float*)outp;
  const int koff = (lane >> 4) * 8;
  const int gr0 = row0 + wid * 32 + (lane & 15);
  const bool v0 = gr0 < M, v1 = (gr0 + 16) < M;
  const _Float16* a0 = in + (size_t)gr0 * KP + koff;
  const _Float16* a1 = a0 + (size_t)16 * KP;
  const _Float16* bp = wt + (size_t)(lane & 15) * KP + koff;

  if (BLDS) {
    for (int i = tid; i < 5 * NS * 64; i += 256) {
      int l = i & 63;
      int nf = (i >> 6) % 5;
      int s = i / 320;
      int r = nf * 16 + (l & 15);
      int k = s * 32 + ((l >> 4) << 3);
      *reinterpret_cast<uint4*>(&Bs[(size_t)i * 8]) =
          *reinterpret_cast<const uint4*>(wt + (size_t)r * KP + k);
    }
    __syncthreads();
  }

  const f16x8 zf = {0, 0, 0, 0, 0, 0, 0, 0};
  const f32x4 z4 = {0.f, 0.f, 0.f, 0.f};
  f32x4 acc[2][5];
#pragma unroll
  for (int a = 0; a < 2; ++a)
#pragma unroll
    for (int b = 0; b < 5; ++b) acc[a][b] = z4;

#pragma unroll
  for (int s = 0; s < NS; ++s) {
    f16x8 af0 = v0 ? *reinterpret_cast<const f16x8*>(a0 + s * 32) : zf;
    f16x8 af1 = v1 ? *reinterpret_cast<const f16x8*>(a1 + s * 32) : zf;
    f16x8 bf[5];
#pragma unroll
    for (int nf = 0; nf < 5; ++nf) {
      if (BLDS)
        bf[nf] = *reinterpret_cast<const f16x8*>(&Bs[((size_t)(s * 5 + nf) * 64 + lane) * 8]);
      else
        bf[nf] = *reinterpret_cast<const f16x8*>(bp + (size_t)nf * 16 * KP + s * 32);
    }
#pragma unroll
    for (int nf = 0; nf < 5; ++nf) {
      acc[0][nf] = __builtin_amdgcn_mfma_f32_16x16x32_f16(af0, bf[nf], acc[0][nf], 0, 0, 0);
      acc[1][nf] = __builtin_amdgcn_mfma_f32_16x16x32_f16(af1, bf[nf], acc[1][nf], 0, 0, 0);
    }
  }

  if constexpr (TSTORE) {
    __syncthreads();
    _Float16* Os = (_Float16*)smem;
#pragma unroll
    for (int rf = 0; rf < 2; ++rf) {
#pragma unroll
      for (int j = 0; j < 4; ++j) {
        int rl = wid * 32 + rf * 16 + (lane >> 4) * 4 + j;
#pragma unroll
        for (int nf = 0; nf < 5; ++nf) {
          int cl = nf * 16 + (lane & 15);
          int oc = col0 + cl;
          float r = 0.f;
          if (oc < Nout) r = fmaxf(acc[rf][nf][j] + bo[oc], 0.f);
          Os[rl * 80 + cl] = (_Float16)r;
        }
      }
    }
    __syncthreads();
    for (int i = tid; i < 1280; i += 256) {
      int rl = i / 10, u = i - rl * 10;
      int gr = row0 + rl;
      if (gr < M)
        *reinterpret_cast<uint4*>(&out16[(size_t)gr * LDO + col0 + u * 8]) =
            *reinterpret_cast<const uint4*>(&Os[rl * 80 + u * 8]);
    }
  } else {
#pragma unroll
    for (int rf = 0; rf < 2; ++rf) {
#pragma unroll
      for (int j = 0; j < 4; ++j) {
        int gr = row0 + wid * 32 + rf * 16 + (lane >> 4) * 4 + j;
        if (gr >= M) continue;
#pragma unroll
        for (int nf = 0; nf < 5; ++nf) {
          int oc = col0 + nf * 16 + (lane & 15);
          if (oc >= Nout) continue;
          float v = acc[rf][nf][j];
          if (OUT_MODE == 1) out16[(size_t)gr * LDO + oc] = (_Float16)fmaxf(v + bo[oc], 0.f);
          else out32[(size_t)gr * LDO + oc] = v + bo[oc];
        }
      }
    }
  }
}

__device__ inline void acc8(float* a, uint4 v) {
  const __half2* h = reinterpret_cast<const __half2*>(&v);
#pragma unroll
  for (int j = 0; j < 4; ++j) {
    float2 f = __half22float2(h[j]);
    a[2 * j] += f.x;
    a[2 * j + 1] += f.y;
  }
}

// segment-sum gather; rows stride LDI f16 from hbase
template <int LDI>
__device__ inline void gather_sumT(float* a, const _Float16* hbase, unsigned n,
                                   const int4* __restrict__ ell,
                                   const int* __restrict__ rowptr,
                                   const int* __restrict__ ssrc) {
  int4 e = ell[n];
  const int deg = e.x;
  uint4 sv = *reinterpret_cast<const uint4*>(hbase + (size_t)n * LDI);
  uint4 g0, g1, g2;
  if (deg > 0) g0 = *reinterpret_cast<const uint4*>(hbase + (size_t)e.y * LDI);
  if (deg > 1) g1 = *reinterpret_cast<const uint4*>(hbase + (size_t)e.z * LDI);
  if (deg > 2) g2 = *reinterpret_cast<const uint4*>(hbase + (size_t)e.w * LDI);
  {
    const __half2* h = reinterpret_cast<const __half2*>(&sv);
#pragma unroll
    for (int j = 0; j < 4; ++j) {
      float2 f = __half22float2(h[j]);
      a[2 * j] = f.x;
      a[2 * j + 1] = f.y;
    }
  }
  if (deg > 0) acc8(a, g0);
  if (deg > 1) acc8(a, g1);
  if (deg > 2) acc8(a, g2);
  if (deg > 3) {
    int r = rowptr[n] + 3, r1 = r + deg - 3;
    for (; r + 2 <= r1; r += 2) {
      uint4 va = *reinterpret_cast<const uint4*>(hbase + (size_t)ssrc[r] * LDI);
      uint4 vb = *reinterpret_cast<const uint4*>(hbase + (size_t)ssrc[r + 1] * LDI);
      acc8(a, va);
      acc8(a, vb);
    }
    if (r < r1) {
      uint4 va = *reinterpret_cast<const uint4*>(hbase + (size_t)ssrc[r] * LDI);
      acc8(a, va);
    }
  }
}

// Input-side aggregation: Z[n] = f16(dinv[n] * (in[n] + Σ_seg in[ssrc]))
// NSUB covers only the USEFUL columns (pads beyond NSUB*8 are never read with
// nonzero weights, so they may hold stale finite data).
template <int LDI, int NSUB>
__global__ __launch_bounds__(256) void aggregateZ(
    const _Float16* __restrict__ in, const int4* __restrict__ ell,
    const int* __restrict__ rowptr, const int* __restrict__ ssrc,
    const float* __restrict__ dinv, _Float16* __restrict__ outZ, int ldo) {
  unsigned idx = blockIdx.x * 256u + threadIdx.x;
  if (idx >= (unsigned)N_NODES * NSUB) return;
  unsigned n = idx / NSUB, sub = idx - n * NSUB;
  float a[8];
  gather_sumT<LDI>(a, in + sub * 8u, n, ell, rowptr, ssrc);
  float di = dinv[n];
  _Float16 ov[8];
#pragma unroll
  for (int j = 0; j < 8; ++j) ov[j] = (_Float16)(di * a[j]);
  *reinterpret_cast<uint4*>(outZ + (size_t)n * ldo + sub * 8u) =
      *reinterpret_cast<const uint4*>(ov);
}

// Mean-pool over contiguous node range, 16B/thread (20 threads/graph, full
// 160-wide row of O3 stride 168): GA[g*320 + coffGA + q*8..] = (1/cnt) Σ_n ...
__global__ __launch_bounds__(256) void pool_seq20(
    const _Float16* __restrict__ in, const int* __restrict__ gstart,
    _Float16* __restrict__ GA, int coffGA) {
  unsigned idx = blockIdx.x * 256u + threadIdx.x;
  if (idx >= (unsigned)N_GRAPHS * 20u) return;
  unsigned g = idx / 20u, q = idx - g * 20u;
  int n0 = gstart[g], n1 = gstart[g + 1];
  const _Float16* base = in + q * 8;
  float a[8] = {0.f, 0.f, 0.f, 0.f, 0.f, 0.f, 0.f, 0.f};
  float b2[8] = {0.f, 0.f, 0.f, 0.f, 0.f, 0.f, 0.f, 0.f};
  int n = n0;
  for (; n + 2 <= n1; n += 2) {
    uint4 va = *reinterpret_cast<const uint4*>(base + (size_t)n * 168);
    uint4 vb = *reinterpret_cast<const uint4*>(base + (size_t)(n + 1) * 168);
    acc8(a, va);
    acc8(b2, vb);
  }
  if (n < n1) {
    uint4 va = *reinterpret_cast<const uint4*>(base + (size_t)n * 168);
    acc8(a, va);
  }
  float gi = 1.0f / fmaxf((float)(n1 - n0), 1.0f);
  _Float16 ov[8];
#pragma unroll
  for (int j = 0; j < 8; ++j) ov[j] = (_Float16)((a[j] + b2[j]) * gi);
  *reinterpret_cast<uint4*>(GA + (size_t)g * 320 + coffGA + q * 8) =
      *reinterpret_cast<const uint4*>(ov);
}

extern "C" void kernel_launch(void* const* d_in, const int* in_sizes, int n_in,
                              void* d_out, int out_size, void* d_ws, size_t ws_size,
                              hipStream_t stream) {
  const float* x   = (const float*)d_in[0];
  const int* ei    = (const int*)d_in[1];
  const int* batch = (const int*)d_in[2];
  const float* W1 = (const float*)d_in[3];
  const float* b1 = (const float*)d_in[4];
  const float* W2 = (const float*)d_in[5];
  const float* b2 = (const float*)d_in[6];
  const float* W3 = (const float*)d_in[7];
  const float* b3 = (const float*)d_in[8];
  const float* fW1 = (const float*)d_in[9];
  const float* fb1 = (const float*)d_in[10];
  const float* fW2 = (const float*)d_in[11];
  const float* fb2 = (const float*)d_in[12];
  float* out = (float*)d_out;

  const int Nn = N_NODES, E = N_EDGES, G = N_GRAPHS;
  const int* src = ei;
  const int* dst = ei + E;

  // ---- workspace layout (~370 MB): A/B ping-pong, stride 168 ----
  _Float16* A = (_Float16*)d_ws;                          // [N,168]
  _Float16* B = A + (size_t)Nn * 168;                     // [N,168]
  _Float16* GA = B + (size_t)Nn * 168;                    // [G,320] chunk80
  _Float16* W1T   = GA + (size_t)G * 320;                 // [96][104]
  _Float16* W2T   = W1T + 96 * 104;                       // [160][104]
  _Float16* W3T   = W2T + 160 * 104;                      // [320][168] chunk80
  _Float16* fW1T  = W3T + 320 * 168;                      // [1040][320] chunk80
  _Float16* fW2T  = fW1T + (size_t)1040 * 320;            // [160][1056]
  float* dinv     = (float*)(fW2T + (size_t)160 * 1056);  // [N]
  int* rowptr     = (int*)(dinv + Nn);                    // [N+1]
  int* cur        = rowptr + Nn + 1;                      // [N]
  int* ssrc       = cur + Nn;                             // [E]
  int* partials   = ssrc + E;                             // [512]
  int* gstart     = partials + 512;                       // [G+1]
  int4* ell = (int4*)(((uintptr_t)(gstart + G + 1) + 15) & ~(uintptr_t)15);  // [N]

  _Float16* Xh = A;      // [N,104]
  _Float16* Z1 = B;      // [N,104]
  _Float16* H1 = A;      // [N,104]
  _Float16* Z2 = B;      // [N,104]
  _Float16* H2 = A;      // [N,168]
  _Float16* Z3 = B;      // [N,168]
  _Float16* O3 = A;      // [N,168] per L3 pass
  _Float16* fc1 = B;     // [G,1056]

  dim3 blk(256);
  const int gN10 = (int)(((unsigned)Nn * 10u + 255u) / 256u);
  const int gN20 = (int)(((unsigned)Nn * 20u + 255u) / 256u);
  const int gG20 = (int)(((unsigned)G * 20u + 255u) / 256u);
  const dim3 oneGrid(1, (Nn + 63) / 64);    // 7813
  const dim3 pairGrid(2, (Nn + 63) / 64);
  const int NB = (Nn + 1023) / 1024;  // 489

  // ---- CSR build + fused finalize (dinv/ell/gstart) ----
  fill_u32<<<(Nn + 255) / 256, blk, 0, stream>>>((unsigned*)cur, 0u, Nn);
  hist_dst<<<(E + 255) / 256, blk, 0, stream>>>(dst, cur, E);
  scanA<<<NB, blk, 0, stream>>>(cur, rowptr, partials, Nn);
  scanB<<<1, 512, 0, stream>>>(partials, NB);
  scanC<<<(Nn + 255) / 256, blk, 0, stream>>>(rowptr, partials, cur, Nn, E);
  bucket<<<(E + 255) / 256, blk, 0, stream>>>(src, dst, cur, ssrc, E);
  finalize_graph<<<(Nn + 256) / 256, blk, 0, stream>>>(rowptr, ssrc, batch, dinv, ell, gstart, Nn);

  // ---- fp16 transposed weights (zero-padded rows/cols) ----
  wt_conv<0><<<(96 * 104 + 255) / 256, blk, 0, stream>>>(W1, W1T, 78, 78, 78, 96, 104, 96 * 104);
  wt_conv<0><<<(160 * 104 + 255) / 256, blk, 0, stream>>>(W2, W2T, 78, 156, 156, 96, 104, 160 * 104);
  wt_conv<80><<<(320 * 168 + 255) / 256, blk, 0, stream>>>(W3, W3T, 156, 312, 312, 160, 168, 320 * 168);
  wt_conv<80><<<(1040 * 320 + 255) / 256, blk, 0, stream>>>(fW1, fW1T, 312, 1024, 1024, 320, 320, 1040 * 320);
  wt_conv<0><<<(160 * 1056 + 255) / 256, blk, 0, stream>>>(fW2, fW2T, 1024, 128, 128, 1056, 1056, 160 * 1056);

  // ---- x -> f16 X' = D X [N,104] (zero pad) ----
  xconv<<<(int)(((unsigned)Nn * 52u + 255u) / 256u), blk, 0, stream>>>(x, dinv, Xh);

  // ---- layer 1: Z1 = D(I+A)X' (80 cols) ; H1 = relu(Z1 W1 + b1) * dinv ----
  aggregateZ<104, 10><<<gN10, blk, 0, stream>>>(Xh, ell, rowptr, ssrc, dinv, Z1, 104);
  gemm_lds<96, 104, 3><<<oneGrid, blk, 0, stream>>>(Z1, W1T, H1, dinv, b1, Nn, 104);

  // ---- layer 2: Z2 = D(I+A)H1 (80 cols) ; H2 = relu(Z2 W2 + b2)*dinv (2 planes) ----
  aggregateZ<104, 10><<<gN10, blk, 0, stream>>>(H1, ell, rowptr, ssrc, dinv, Z2, 104);
  gemm_lds<96, 104, 3><<<pairGrid, blk, 0, stream>>>(Z2, W2T, H2, dinv, b2, Nn, 168);

  // ---- layer 3: Z3 = D(I+A)H2 (160 cols) ; 2 passes: O3 -> fused pool ----
  aggregateZ<168, 20><<<gN20, blk, 0, stream>>>(H2, ell, rowptr, ssrc, dinv, Z3, 168);
  for (int p = 0; p < 2; ++p) {
    gemm_lds<160, 168, 1><<<pairGrid, blk, 0, stream>>>(
        Z3, W3T + (size_t)(156 * p) * 168, O3, nullptr, b3 + 156 * p, Nn, 168);
    pool_seq20<<<gG20, blk, 0, stream>>>(O3, gstart, GA, p * 160);
  }

  // ---- FC1: relu(GA @ fW1 + fb1) -> fc1 f16 (B staged in 50 KB LDS) ----
  {
    dim3 g((1024 + 79) / 80, (G + 127) / 128);  // 13 x 157
    gemm_direct<320, 1, 1><<<g, blk, 0, stream>>>(GA, fW1T, fc1, fb1, G, 1024, 1056);
  }
  // ---- FC2: out = fc1 @ fW2 + fb2 (f32) ----
  {
    dim3 g((128 + 79) / 80, (G + 127) / 128);  // 2 x 157
    gemm_direct<1056, 2, 0><<<g, blk, 0, stream>>>(fc1, fW2T, out, fb2, G, 128, 128);
  }
}